// Round 6
// baseline (258.926 us; speedup 1.0000x reference)
//
#include <hip/hip_runtime.h>
#include <hip/hip_bf16.h>

#define N_NODES 50000
#define N_EDGES 800000
#define N_RELS  8
#define NBUCK   3125         // 16 nodes per bucket
#define NPART   8            // XCD partitions
#define BCAPP   96           // per (partition,bucket) cap: mean 32, +11 sigma
#define NBLK    782          // ceil(NBUCK/4): 4 buckets (64 nodes) per block

typedef __attribute__((ext_vector_type(8))) short bf16x8;
typedef __attribute__((ext_vector_type(4))) float f32x4;
typedef __attribute__((ext_vector_type(2))) float f32x2;

__device__ __forceinline__ unsigned short f2b(float f) {
    unsigned int u = __float_as_uint(f);
    u += 0x7fffu + ((u >> 16) & 1u);
    return (unsigned short)(u >> 16);
}

// ---- prep: cvt_w->frag layout (blocks 0..511) | bin (512..3636) ----
// h is no longer converted: the gather reads f32 rows of h directly.
__global__ void prep_kernel(const float* __restrict__ w, unsigned short* __restrict__ wt2,
                            const int* __restrict__ src, const int* __restrict__ dst,
                            const int* __restrict__ et, const float* __restrict__ en,
                            int* __restrict__ bucketCnt, unsigned int* __restrict__ bins) {
    int b = blockIdx.x;
    if (b < 512) {
        int idx = b * 256 + threadIdx.x;             // 131072 = 8*128*128
        int r = idx >> 14;
        int k = (idx >> 7) & 127;
        int o = idx & 127;
        // wt2[r][o>>4][k>>3][o&15][k&7]
        int off = (r << 14) + ((o >> 4) << 11) + ((k >> 3) << 7) + ((o & 15) << 3) + (k & 7);
        wt2[off] = f2b(w[idx]);
    } else {
        int e = (b - 512) * 256 + threadIdx.x;       // 800000
        int part = b & 7;                            // ~physical XCD (512%8==0 keeps round-robin)
        int d = dst[e];
        int bk = d >> 4;
        int key = (et[e] << 4) | (d & 15);           // relation-major, 0..127
        int q = (int)(en[e] * 512.0f); if (q > 511) q = 511;
        int cell = part * NBUCK + bk;
        int pos = atomicAdd(&bucketCnt[cell], 1);
        if (pos < BCAPP)
            bins[cell * BCAPP + pos] = ((unsigned)src[e] << 16) | ((unsigned)key << 9) | (unsigned)q;
    }
}

// ---- fused M=64: block = 4 buckets, 512 threads, ~35KB LDS -> 4 blocks/CU.
//      Gather: 8-edge batches, NAMED-SCALAR f32x2 loads (saddr form) -- no arrays
//      near asm, so nothing can go to scratch (round-5 spill: VGPR=32 + 82MB
//      scratch writes). Reads h (f32) directly; hb eliminated. ----
__global__ __launch_bounds__(512, 8) void fused_kernel(const float* __restrict__ h,
                                                       const unsigned int* __restrict__ bins,
                                                       const int* __restrict__ bucketCnt,
                                                       const char* __restrict__ wt2,
                                                       const float* __restrict__ bias,
                                                       float* __restrict__ out) {
    __shared__ __align__(16) unsigned int sMeta[4 * 768];  // sorted (src<<16)|(key<<9)|q9
    __shared__ int hist[512];                        // 4 x 128 keys
    __shared__ int segS[4 * 132];                    // 4 x (128 seg starts + total)
    __shared__ int cursor[512];
    __shared__ __align__(16) char aggT[16384];       // [64 nodes][128 bf16], swizzled
    const int b = blockIdx.x;
    const int tid = threadIdx.x;
    const int g = tid >> 7, gtid = tid & 127;        // 128-thread group per bucket
    const int bk = b * 4 + g;
    const bool bv = (bk < NBUCK);

    hist[tid] = 0;
    __syncthreads();

    unsigned rec[NPART];
    bool have[NPART];
    #pragma unroll
    for (int p = 0; p < NPART; ++p) {
        int c = bv ? bucketCnt[p * NBUCK + bk] : 0;
        if (c > BCAPP) c = BCAPP;
        have[p] = (gtid < c);
        rec[p] = 0;
        if (have[p]) {
            rec[p] = bins[(p * NBUCK + bk) * BCAPP + gtid];
            atomicAdd(&hist[g * 128 + ((rec[p] >> 9) & 127)], 1);
        }
    }
    __syncthreads();

    // per-group inclusive scan over 128 keys (groups lockstep; block-wide barriers)
    int v = hist[tid];
    __syncthreads();
    #pragma unroll
    for (int off = 1; off < 128; off <<= 1) {
        int t = (gtid >= off) ? hist[tid - off] : 0;
        __syncthreads();
        hist[tid] += t;
        __syncthreads();
    }
    int exc = hist[tid] - v;
    segS[g * 132 + gtid] = exc;
    cursor[tid] = exc;
    if (gtid == 127) segS[g * 132 + 128] = hist[tid];
    __syncthreads();

    #pragma unroll
    for (int p = 0; p < NPART; ++p)
        if (have[p]) {
            int key = (rec[p] >> 9) & 127;
            int pos = atomicAdd(&cursor[g * 128 + key], 1);
            sMeta[g * 768 + pos] = rec[p];
        }
    __syncthreads();

    // ---- r-outer: batched-ILP aggregate(r) -> aggT; barrier; MFMA(r); barrier ----
    const int wave = tid >> 6, lane = tid & 63;
    const int m16 = lane & 15, quad = lane >> 4;
    const int wg = wave >> 1, half = wave & 1;       // wave's bucket + node-half
    const unsigned int* sm = &sMeta[wg * 768];
    const int* seg = &segS[wg * 132];
    const unsigned loff = (unsigned)(lane << 3);     // byte offset in 512B f32 row
    const char* hp = (const char*)h;

    f32x4 acc[4];
    #pragma unroll
    for (int ng = 0; ng < 4; ++ng) acc[ng] = (f32x4){0.f, 0.f, 0.f, 0.f};

    for (int r = 0; r < N_RELS; ++r) {
        const int jbase = r * 16 + half * 8;         // seg index of (r, first own node)
        int ws_ = __builtin_amdgcn_readfirstlane(seg[jbase]);
        int we_ = __builtin_amdgcn_readfirstlane(seg[jbase + 8]);
        int j = 0;
        int je = __builtin_amdgcn_readfirstlane(seg[jbase + 1]);
        float ax = 0.f, ay = 0.f;

        for (int k0 = ws_ & ~7; k0 < we_; k0 += 8) {
            // 8 records via 2 uniform 16B LDS reads (32B-aligned: k0 % 8 == 0)
            const uint4* sm4 = (const uint4*)(sm + k0);
            uint4 ra = sm4[0], rb = sm4[1];
            f32x2 f0, f1, f2, f3, f4, f5, f6, f7;
            // uniform-guarded volatile loads (saddr form: 1 VGPR offset + SGPR base)
#define GLD(i, ff, qq) if (k0 + (i) >= ws_ && k0 + (i) < we_) \
            asm volatile("global_load_dwordx2 %0, %1, %2" : "=v"(ff) \
                : "v"((((qq) >> 16) << 9) + loff), "s"(hp) : "memory")
            GLD(0, f0, ra.x); GLD(1, f1, ra.y); GLD(2, f2, ra.z); GLD(3, f3, ra.w);
            GLD(4, f4, rb.x); GLD(5, f5, rb.y); GLD(6, f6, rb.z); GLD(7, f7, rb.w);
#undef GLD
            asm volatile("s_waitcnt vmcnt(0)" ::: "memory");
            __builtin_amdgcn_sched_barrier(0);       // rule #18
            // accumulate in sorted order; flush on (uniform) node boundary
#define ACC(i, ff, qq) { int k = k0 + (i); \
            if (k >= ws_ && k < we_) { \
                while (k >= je && j < 7) { \
                    int ln = half * 8 + j; \
                    int sw = (((lane >> 2) ^ ln) << 4) + (lane & 3) * 4; \
                    unsigned u = (unsigned)f2b(ax) | ((unsigned)f2b(ay) << 16); \
                    *(unsigned*)(aggT + (wg * 16 + ln) * 256 + sw) = u; \
                    ax = 0.f; ay = 0.f; ++j; \
                    je = __builtin_amdgcn_readfirstlane(seg[jbase + j + 1]); \
                } \
                float w0 = (float)((qq) & 0x1ffu) * (1.f / 512.f) + (1.f / 1024.f); \
                ax += ff.x * w0; ay += ff.y * w0; } }
            ACC(0, f0, ra.x); ACC(1, f1, ra.y); ACC(2, f2, ra.z); ACC(3, f3, ra.w);
            ACC(4, f4, rb.x); ACC(5, f5, rb.y); ACC(6, f6, rb.z); ACC(7, f7, rb.w);
#undef ACC
        }
        // flush node j and all remaining (possibly empty) nodes up to 7
        for (;;) {
            int ln = half * 8 + j;
            int sw = (((lane >> 2) ^ ln) << 4) + (lane & 3) * 4;
            unsigned u = (unsigned)f2b(ax) | ((unsigned)f2b(ay) << 16);
            *(unsigned*)(aggT + (wg * 16 + ln) * 256 + sw) = u;
            ax = 0.f; ay = 0.f;
            if (j == 7) break;
            ++j;
        }

        // prefetch this wave's W fragments (og = wave); latency drains at barrier
        bf16x8 wf[4];
        #pragma unroll
        for (int kk = 0; kk < 4; ++kk)
            wf[kk] = *(const bf16x8*)(wt2 + (r << 15) + (wave << 12) + (((kk << 2) + quad) << 8) + (m16 << 4));
        __syncthreads();   // agg(r) visible to all waves
        #pragma unroll
        for (int kk = 0; kk < 4; ++kk) {
            int cc = (kk << 2) + quad;
            #pragma unroll
            for (int ng = 0; ng < 4; ++ng) {
                bf16x8 bf = *(const bf16x8*)(aggT + ((ng * 16 + m16) << 8) + ((cc ^ m16) << 4));
                acc[ng] = __builtin_amdgcn_mfma_f32_16x16x32_bf16(wf[kk], bf, acc[ng], 0, 0, 0);
            }
        }
        if (r + 1 < N_RELS) __syncthreads();         // all reads done before next r's writes
    }

    // epilogue: wave owns o-range [wave*16, +16); acc[ng] covers nodes ng*16..+15
    #pragma unroll
    for (int ng = 0; ng < 4; ++ng) {
        int n = b * 64 + ng * 16 + m16;
        if (n < N_NODES) {
            int o = wave * 16 + quad * 4;
            float4 b4 = *(const float4*)&bias[o];
            float4 vv;
            vv.x = fmaxf(acc[ng][0] + b4.x, 0.f);
            vv.y = fmaxf(acc[ng][1] + b4.y, 0.f);
            vv.z = fmaxf(acc[ng][2] + b4.z, 0.f);
            vv.w = fmaxf(acc[ng][3] + b4.w, 0.f);
            *(float4*)&out[(size_t)n * 128 + o] = vv;
        }
    }
}

extern "C" void kernel_launch(void* const* d_in, const int* in_sizes, int n_in,
                              void* d_out, int out_size, void* d_ws, size_t ws_size,
                              hipStream_t stream) {
    const float* h    = (const float*)d_in[0];
    const float* en   = (const float*)d_in[1];
    const int*   et   = (const int*)d_in[2];
    const int*   src  = (const int*)d_in[3];
    const int*   dst  = (const int*)d_in[4];
    const float* w    = (const float*)d_in[5];
    const float* bias = (const float*)d_in[6];
    float* out = (float*)d_out;

    char* ws = (char*)d_ws;
    unsigned short* wt2 = (unsigned short*)(ws);                 //     262,144 B
    int*          bucketCnt = (int*)(ws + 262144);               //     100,000 B (8 * 3125)
    unsigned int* bins      = (unsigned int*)(ws + 362144);      //   9,600,000 B (8*3125*96*4)

    (void)hipMemsetAsync(bucketCnt, 0, NPART * NBUCK * sizeof(int), stream);
    hipLaunchKernelGGL(prep_kernel, dim3(3637), dim3(256), 0, stream,
                       w, wt2, src, dst, et, en, bucketCnt, bins);
    hipLaunchKernelGGL(fused_kernel, dim3(NBLK), dim3(512), 0, stream,
                       h, bins, bucketCnt, (const char*)wt2, bias, out);
}

// Round 7
// 216.211 us; speedup vs baseline: 1.1976x; 1.1976x over previous
//
#include <hip/hip_runtime.h>
#include <hip/hip_bf16.h>

#define N_NODES 50000
#define N_EDGES 800000
#define N_RELS  8
#define NBUCK   3125         // 16 nodes per bucket
#define NPART   8            // XCD partitions
#define BCAPP   96           // per (partition,bucket) cap: mean 32, +11 sigma
#define NBLK    782          // ceil(NBUCK/4): 4 buckets (64 nodes) per block

typedef __attribute__((ext_vector_type(8))) short bf16x8;
typedef __attribute__((ext_vector_type(4))) float f32x4;

__device__ __forceinline__ unsigned short f2b(float f) {
    unsigned int u = __float_as_uint(f);
    u += 0x7fffu + ((u >> 16) & 1u);
    return (unsigned short)(u >> 16);
}

// ---- prep: cvt_h (0..6249) | cvt_w->frag (6250..6761) | bin (6762..9886) ----
// hb (bf16 256B rows) RESTORED: f32 rows doubled gather FETCH in round 6.
__global__ void prep_kernel(const float* __restrict__ h, unsigned short* __restrict__ hb,
                            const float* __restrict__ w, unsigned short* __restrict__ wt2,
                            const int* __restrict__ src, const int* __restrict__ dst,
                            const int* __restrict__ et, const float* __restrict__ en,
                            int* __restrict__ bucketCnt, unsigned int* __restrict__ bins) {
    int b = blockIdx.x;
    if (b < 6250) {
        int i = b * 256 + threadIdx.x;               // 1,600,000 float4 chunks
        float4 v = ((const float4*)h)[i];
        ushort4 o;
        o.x = f2b(v.x); o.y = f2b(v.y); o.z = f2b(v.z); o.w = f2b(v.w);
        ((ushort4*)hb)[i] = o;
    } else if (b < 6762) {
        int idx = (b - 6250) * 256 + threadIdx.x;    // 131072 = 8*128*128
        int r = idx >> 14;
        int k = (idx >> 7) & 127;
        int o = idx & 127;
        // wt2[r][o>>4][k>>3][o&15][k&7]
        int off = (r << 14) + ((o >> 4) << 11) + ((k >> 3) << 7) + ((o & 15) << 3) + (k & 7);
        wt2[off] = f2b(w[idx]);
    } else {
        int e = (b - 6762) * 256 + threadIdx.x;      // 800000
        int part = b & 7;                            // ~physical XCD (round-robin dispatch)
        int d = dst[e];
        int bk = d >> 4;
        int key = (et[e] << 4) | (d & 15);           // relation-major, 0..127
        int q = (int)(en[e] * 512.0f); if (q > 511) q = 511;
        int cell = part * NBUCK + bk;
        int pos = atomicAdd(&bucketCnt[cell], 1);
        if (pos < BCAPP)
            bins[cell * BCAPP + pos] = ((unsigned)src[e] << 16) | ((unsigned)key << 9) | (unsigned)q;
    }
}

// ---- fused M=64: block = 4 buckets, 512 threads, ~35KB LDS.
//      Gather: 8-edge batches, named-scalar dword loads, NO inline asm (asm
//      variants spilled: r5/r6 VGPR=32 + 80-160MB scratch). Clustering enforced
//      by ONE sched_barrier(0) between the 8 loads and their uses.
//      (512,6): VGPR cap ~85 -- room for the batch; grid only fills 3 blk/CU. ----
__global__ __launch_bounds__(512, 6) void fused_kernel(const char* __restrict__ hb,
                                                       const unsigned int* __restrict__ bins,
                                                       const int* __restrict__ bucketCnt,
                                                       const char* __restrict__ wt2,
                                                       const float* __restrict__ bias,
                                                       float* __restrict__ out) {
    __shared__ __align__(16) unsigned int sMeta[4 * 768];  // sorted (src<<16)|(key<<9)|q9
    __shared__ int hist[512];                        // 4 x 128 keys
    __shared__ int segS[4 * 132];                    // 4 x (128 seg starts + total)
    __shared__ int cursor[512];
    __shared__ __align__(16) char aggT[16384];       // [64 nodes][128 bf16], swizzled
    const int b = blockIdx.x;
    const int tid = threadIdx.x;
    const int g = tid >> 7, gtid = tid & 127;        // 128-thread group per bucket
    const int bk = b * 4 + g;
    const bool bv = (bk < NBUCK);

    hist[tid] = 0;
    __syncthreads();

    unsigned rec[NPART];
    bool have[NPART];
    #pragma unroll
    for (int p = 0; p < NPART; ++p) {
        int c = bv ? bucketCnt[p * NBUCK + bk] : 0;
        if (c > BCAPP) c = BCAPP;
        have[p] = (gtid < c);
        rec[p] = 0;
        if (have[p]) {
            rec[p] = bins[(p * NBUCK + bk) * BCAPP + gtid];
            atomicAdd(&hist[g * 128 + ((rec[p] >> 9) & 127)], 1);
        }
    }
    __syncthreads();

    // per-group inclusive scan over 128 keys (groups lockstep; block-wide barriers)
    int v = hist[tid];
    __syncthreads();
    #pragma unroll
    for (int off = 1; off < 128; off <<= 1) {
        int t = (gtid >= off) ? hist[tid - off] : 0;
        __syncthreads();
        hist[tid] += t;
        __syncthreads();
    }
    int exc = hist[tid] - v;
    segS[g * 132 + gtid] = exc;
    cursor[tid] = exc;
    if (gtid == 127) segS[g * 132 + 128] = hist[tid];
    __syncthreads();

    #pragma unroll
    for (int p = 0; p < NPART; ++p)
        if (have[p]) {
            int key = (rec[p] >> 9) & 127;
            int pos = atomicAdd(&cursor[g * 128 + key], 1);
            sMeta[g * 768 + pos] = rec[p];
        }
    __syncthreads();

    // ---- r-outer: batched-ILP aggregate(r) -> aggT; barrier; MFMA(r); barrier ----
    const int wave = tid >> 6, lane = tid & 63;
    const int m16 = lane & 15, quad = lane >> 4;
    const int wg = wave >> 1, half = wave & 1;       // wave's bucket + node-half
    const unsigned int* sm = &sMeta[wg * 768];
    const int* seg = &segS[wg * 132];
    const int l4 = lane << 2;                        // byte offset in 256B bf16 row

    f32x4 acc[4];
    #pragma unroll
    for (int ng = 0; ng < 4; ++ng) acc[ng] = (f32x4){0.f, 0.f, 0.f, 0.f};

    for (int r = 0; r < N_RELS; ++r) {
        const int jbase = r * 16 + half * 8;         // seg index of (r, first own node)
        int ws_ = __builtin_amdgcn_readfirstlane(seg[jbase]);
        int we_ = __builtin_amdgcn_readfirstlane(seg[jbase + 8]);
        int j = 0;
        int je = __builtin_amdgcn_readfirstlane(seg[jbase + 1]);
        float ax = 0.f, ay = 0.f;

        for (int k0 = ws_ & ~7; k0 < we_; k0 += 8) {
            // 8 records via 2 uniform 16B LDS reads (32B-aligned: k0 % 8 == 0)
            const uint4* sm4 = (const uint4*)(sm + k0);
            uint4 ra = sm4[0], rb = sm4[1];
            unsigned v0 = 0, v1 = 0, v2 = 0, v3 = 0, v4 = 0, v5 = 0, v6 = 0, v7 = 0;
            // issue all in-range row loads (uniform guards), THEN fence motion:
#define GLD(i, vv, qq) if (k0 + (i) >= ws_ && k0 + (i) < we_) \
            vv = *(const unsigned*)(hb + (((int)((qq) >> 16)) << 8) + l4)
            GLD(0, v0, ra.x); GLD(1, v1, ra.y); GLD(2, v2, ra.z); GLD(3, v3, ra.w);
            GLD(4, v4, rb.x); GLD(5, v5, rb.y); GLD(6, v6, rb.z); GLD(7, v7, rb.w);
#undef GLD
            __builtin_amdgcn_sched_barrier(0);       // loads stay clustered above (ILP-8)
            // accumulate in sorted order; flush on (uniform) node boundary
#define ACC(i, vv, qq) { int k = k0 + (i); \
            if (k >= ws_ && k < we_) { \
                while (k >= je && j < 7) { \
                    int ln = half * 8 + j; \
                    int sw = (((lane >> 2) ^ ln) << 4) + (lane & 3) * 4; \
                    unsigned u = (unsigned)f2b(ax) | ((unsigned)f2b(ay) << 16); \
                    *(unsigned*)(aggT + (wg * 16 + ln) * 256 + sw) = u; \
                    ax = 0.f; ay = 0.f; ++j; \
                    je = __builtin_amdgcn_readfirstlane(seg[jbase + j + 1]); \
                } \
                float w0 = (float)((qq) & 0x1ffu) * (1.f / 512.f) + (1.f / 1024.f); \
                ax += __uint_as_float(vv << 16) * w0; \
                ay += __uint_as_float(vv & 0xffff0000u) * w0; } }
            ACC(0, v0, ra.x); ACC(1, v1, ra.y); ACC(2, v2, ra.z); ACC(3, v3, ra.w);
            ACC(4, v4, rb.x); ACC(5, v5, rb.y); ACC(6, v6, rb.z); ACC(7, v7, rb.w);
#undef ACC
        }
        // flush node j and all remaining (possibly empty) nodes up to 7
        for (;;) {
            int ln = half * 8 + j;
            int sw = (((lane >> 2) ^ ln) << 4) + (lane & 3) * 4;
            unsigned u = (unsigned)f2b(ax) | ((unsigned)f2b(ay) << 16);
            *(unsigned*)(aggT + (wg * 16 + ln) * 256 + sw) = u;
            ax = 0.f; ay = 0.f;
            if (j == 7) break;
            ++j;
        }

        // prefetch this wave's W fragments (og = wave); latency drains at barrier
        bf16x8 wf[4];
        #pragma unroll
        for (int kk = 0; kk < 4; ++kk)
            wf[kk] = *(const bf16x8*)(wt2 + (r << 15) + (wave << 12) + (((kk << 2) + quad) << 8) + (m16 << 4));
        __syncthreads();   // agg(r) visible to all waves
        #pragma unroll
        for (int kk = 0; kk < 4; ++kk) {
            int cc = (kk << 2) + quad;
            #pragma unroll
            for (int ng = 0; ng < 4; ++ng) {
                bf16x8 bf = *(const bf16x8*)(aggT + ((ng * 16 + m16) << 8) + ((cc ^ m16) << 4));
                acc[ng] = __builtin_amdgcn_mfma_f32_16x16x32_bf16(wf[kk], bf, acc[ng], 0, 0, 0);
            }
        }
        if (r + 1 < N_RELS) __syncthreads();         // all reads done before next r's writes
    }

    // epilogue: wave owns o-range [wave*16, +16); acc[ng] covers nodes ng*16..+15
    #pragma unroll
    for (int ng = 0; ng < 4; ++ng) {
        int n = b * 64 + ng * 16 + m16;
        if (n < N_NODES) {
            int o = wave * 16 + quad * 4;
            float4 b4 = *(const float4*)&bias[o];
            float4 vv;
            vv.x = fmaxf(acc[ng][0] + b4.x, 0.f);
            vv.y = fmaxf(acc[ng][1] + b4.y, 0.f);
            vv.z = fmaxf(acc[ng][2] + b4.z, 0.f);
            vv.w = fmaxf(acc[ng][3] + b4.w, 0.f);
            *(float4*)&out[(size_t)n * 128 + o] = vv;
        }
    }
}

extern "C" void kernel_launch(void* const* d_in, const int* in_sizes, int n_in,
                              void* d_out, int out_size, void* d_ws, size_t ws_size,
                              hipStream_t stream) {
    const float* h    = (const float*)d_in[0];
    const float* en   = (const float*)d_in[1];
    const int*   et   = (const int*)d_in[2];
    const int*   src  = (const int*)d_in[3];
    const int*   dst  = (const int*)d_in[4];
    const float* w    = (const float*)d_in[5];
    const float* bias = (const float*)d_in[6];
    float* out = (float*)d_out;

    char* ws = (char*)d_ws;
    unsigned short* hb  = (unsigned short*)(ws);                 //  12,800,000 B
    unsigned short* wt2 = (unsigned short*)(ws + 12800000);      //     262,144 B
    int*          bucketCnt = (int*)(ws + 13062144);             //     100,000 B (8 * 3125)
    unsigned int* bins      = (unsigned int*)(ws + 13162144);    //   9,600,000 B (8*3125*96*4)

    (void)hipMemsetAsync(bucketCnt, 0, NPART * NBUCK * sizeof(int), stream);
    hipLaunchKernelGGL(prep_kernel, dim3(9887), dim3(256), 0, stream,
                       h, hb, w, wt2, src, dst, et, en, bucketCnt, bins);
    hipLaunchKernelGGL(fused_kernel, dim3(NBLK), dim3(512), 0, stream,
                       (const char*)hb, bins, bucketCnt, (const char*)wt2, bias, out);
}